// Round 1
// baseline (708.727 us; speedup 1.0000x reference)
//
#include <hip/hip_runtime.h>
#include <hip/hip_bf16.h>
#include <stdint.h>

#define T_TOK 32768
#define IN_D  256
#define HID_D 1024
#define OUT_D 256
#define NE    8
#define BM    64
#define HC    64

typedef unsigned short u16;
typedef __attribute__((ext_vector_type(8))) __bf16 bf16x8;
typedef __attribute__((ext_vector_type(4))) float f32x4;
typedef __attribute__((ext_vector_type(4))) unsigned int u32x4;
typedef __attribute__((ext_vector_type(2))) unsigned int u32x2;

__device__ __forceinline__ u16 f2bf(float f) {
  unsigned int u = __builtin_bit_cast(unsigned int, f);
  u = (u + 0x7FFFu + ((u >> 16) & 1u)) >> 16;
  return (u16)u;
}

// ---------------- conversion kernels ----------------
__global__ __launch_bounds__(256) void cvt_x_kernel(const float* __restrict__ x,
                                                    u16* __restrict__ xbf) {
  int i = blockIdx.x * 256 + threadIdx.x;  // over T*IN/4
  f32x4 v = reinterpret_cast<const f32x4*>(x)[i];
  unsigned int lo = (unsigned int)f2bf(v[0]) | ((unsigned int)f2bf(v[1]) << 16);
  unsigned int hi = (unsigned int)f2bf(v[2]) | ((unsigned int)f2bf(v[3]) << 16);
  reinterpret_cast<u32x2*>(xbf)[i] = u32x2{lo, hi};
}

// W1t[e][h][i] = bf16(W1[e][i][h])   (k = i contiguous)
__global__ __launch_bounds__(256) void cvt_w1_kernel(const float* __restrict__ W1,
                                                     u16* __restrict__ w1t) {
  int idx = blockIdx.x * 256 + threadIdx.x;  // over E*HID*IN
  int i = idx & (IN_D - 1);
  int h = (idx >> 8) & (HID_D - 1);
  int e = idx >> 18;
  w1t[idx] = f2bf(W1[((size_t)e * IN_D + i) * HID_D + h]);
}

// W2t[e][o][h] = bf16(W2[e][h][o])   (k = h contiguous)
__global__ __launch_bounds__(256) void cvt_w2_kernel(const float* __restrict__ W2,
                                                     u16* __restrict__ w2t) {
  int idx = blockIdx.x * 256 + threadIdx.x;  // over E*OUT*HID
  int h = idx & (HID_D - 1);
  int o = (idx >> 10) & (OUT_D - 1);
  int e = idx >> 18;
  w2t[idx] = f2bf(W2[((size_t)e * HID_D + h) * OUT_D + o]);
}

// ---------------- router: logits -> softmax -> top2 -> expert lists ----------------
__global__ __launch_bounds__(256) void router_kernel(
    const float* __restrict__ x, const float* __restrict__ Wg,
    float* __restrict__ probs, int* __restrict__ counts,
    int* __restrict__ list_tok, float* __restrict__ list_w) {
  __shared__ float wg_s[IN_D * NE];  // 8 KB, [i][e]
  int tid = threadIdx.x;
  for (int i = tid; i < IN_D * NE; i += 256) wg_s[i] = Wg[i];
  __syncthreads();

  int t = blockIdx.x * 256 + tid;  // grid exact: T/256 blocks
  float acc[NE];
#pragma unroll
  for (int e = 0; e < NE; ++e) acc[e] = 0.f;
  const f32x4* xr = reinterpret_cast<const f32x4*>(x + (size_t)t * IN_D);
  for (int i = 0; i < IN_D / 4; ++i) {
    f32x4 v = xr[i];
#pragma unroll
    for (int j = 0; j < 4; ++j) {
      float xv = v[j];
      const float* wrow = &wg_s[(i * 4 + j) * NE];
#pragma unroll
      for (int e = 0; e < NE; ++e) acc[e] += xv * wrow[e];
    }
  }
  // softmax (fp32, matches reference formula)
  float m = acc[0];
#pragma unroll
  for (int e = 1; e < NE; ++e) m = fmaxf(m, acc[e]);
  float p[NE], s = 0.f;
#pragma unroll
  for (int e = 0; e < NE; ++e) { p[e] = expf(acc[e] - m); s += p[e]; }
  float inv = 1.f / s;
#pragma unroll
  for (int e = 0; e < NE; ++e) {
    p[e] *= inv;
    probs[(size_t)t * NE + e] = p[e];
  }
  // top-2, first-occurrence tie-break (matches jax.lax.top_k)
  int i0 = 0; float p0 = p[0];
#pragma unroll
  for (int e = 1; e < NE; ++e) if (p[e] > p0) { p0 = p[e]; i0 = e; }
  int i1 = -1; float p1 = -1.f;
#pragma unroll
  for (int e = 0; e < NE; ++e) if (e != i0 && p[e] > p1) { p1 = p[e]; i1 = e; }
  float wsum = p0 + p1;
  float w0 = p0 / wsum, w1 = p1 / wsum;

  int pos0 = atomicAdd(&counts[i0], 1);
  list_tok[(size_t)i0 * T_TOK + pos0] = t;
  list_w[(size_t)i0 * T_TOK + pos0] = w0;
  int pos1 = atomicAdd(&counts[i1], 1);
  list_tok[(size_t)i1 * T_TOK + pos1] = t;
  list_w[(size_t)i1 * T_TOK + pos1] = w1;
}

// ---------------- fused expert FFN ----------------
// grid: (T_TOK/BM tiles, NE experts), 256 threads = 4 waves.
// Per block: gather 64 token rows (bf16) into swizzled LDS; for each 64-wide H
// chunk: phase1 H^T = W1t_chunk (A, global) @ X^T (B, LDS), bias+relu, packed
// store into row-major H[t][h] LDS; phase2 out^T += W2t_chunk (A, global) @ H^T
// (B, LDS). Epilogue: atomicAdd w*(acc+b2) into out.
__global__ __launch_bounds__(256, 2) void moe_main_kernel(
    const u16* __restrict__ xbf, const u16* __restrict__ w1t,
    const u16* __restrict__ w2t, const float* __restrict__ b1,
    const float* __restrict__ b2, const int* __restrict__ counts,
    const int* __restrict__ list_tok, const float* __restrict__ list_w,
    float* __restrict__ out) {
  int e = blockIdx.y;
  int cnt = counts[e];
  int base = blockIdx.x * BM;
  if (base >= cnt) return;

  __shared__ __align__(16) u16 Xs[BM * IN_D];  // 32 KB, XOR-swizzled rows (512B)
  __shared__ __align__(16) u16 Hs[BM * HC];    // 8 KB, XOR-swizzled rows (128B)
  __shared__ int toks[BM];
  __shared__ float gw[BM];

  int tid = threadIdx.x;
  int wave = tid >> 6;
  int lane = tid & 63;
  const int l15 = lane & 15;
  const int l4 = lane >> 4;  // 0..3

  if (tid < BM) {
    int idx = base + tid;
    int tk = 0; float w = 0.f;
    if (idx < cnt) { tk = list_tok[(size_t)e * T_TOK + idx]; w = list_w[(size_t)e * T_TOK + idx]; }
    toks[tid] = tk;
    gw[tid] = w;
  }
  __syncthreads();

  // ---- stage gathered X rows into swizzled LDS (2 rows per wave-iter) ----
  {
    int half = lane >> 5;   // 0/1
    int c16 = lane & 31;    // 16B chunk in a 512B row
#pragma unroll
    for (int rr = 0; rr < 16; rr += 2) {
      int r = wave * 16 + rr + half;
      int t = toks[r];
      u32x4 v = *reinterpret_cast<const u32x4*>(xbf + (size_t)t * IN_D + c16 * 8);
      int byte = r * 512 + ((c16 * 16) ^ ((r & 7) << 4));
      *reinterpret_cast<u32x4*>(reinterpret_cast<char*>(Xs) + byte) = v;
    }
  }
  __syncthreads();

  // out^T accumulators: wave owns o in [wave*64, wave*64+64), all 64 t.
  f32x4 acc[4][4];
#pragma unroll
  for (int a = 0; a < 4; ++a)
#pragma unroll
    for (int b = 0; b < 4; ++b) acc[a][b] = f32x4{0.f, 0.f, 0.f, 0.f};

  const int wh = wave >> 1;  // phase-1 h half (0/1)
  const int wt = wave & 1;   // phase-1 t half (0/1)

  for (int hc = 0; hc < HID_D; hc += HC) {
    // ---- phase 1: H^T[hc..hc+63][0..63] ----
    {
      f32x4 accH[2][2];
#pragma unroll
      for (int mf = 0; mf < 2; ++mf)
#pragma unroll
        for (int nf = 0; nf < 2; ++nf) accH[mf][nf] = f32x4{0.f, 0.f, 0.f, 0.f};
#pragma unroll
      for (int kk = 0; kk < 8; ++kk) {
        bf16x8 a[2], b[2];
#pragma unroll
        for (int mf = 0; mf < 2; ++mf) {
          int h = hc + wh * 32 + mf * 16 + l15;
          u32x4 v = *reinterpret_cast<const u32x4*>(
              w1t + ((size_t)(e * HID_D + h)) * IN_D + kk * 32 + l4 * 8);
          a[mf] = __builtin_bit_cast(bf16x8, v);
        }
#pragma unroll
        for (int nf = 0; nf < 2; ++nf) {
          int t = wt * 32 + nf * 16 + l15;
          int byte = t * 512 + (((kk * 32 + l4 * 8) * 2) ^ ((t & 7) << 4));
          u32x4 v = *reinterpret_cast<const u32x4*>(reinterpret_cast<const char*>(Xs) + byte);
          b[nf] = __builtin_bit_cast(bf16x8, v);
        }
#pragma unroll
        for (int mf = 0; mf < 2; ++mf)
#pragma unroll
          for (int nf = 0; nf < 2; ++nf)
            accH[mf][nf] = __builtin_amdgcn_mfma_f32_16x16x32_bf16(a[mf], b[nf], accH[mf][nf], 0, 0, 0);
      }
      // bias + relu + packed store into H[t][h'] (row-major, swizzled)
#pragma unroll
      for (int mf = 0; mf < 2; ++mf) {
        int hb = wh * 32 + mf * 16 + l4 * 4;  // h' base, 4 consecutive h
        f32x4 bias = *reinterpret_cast<const f32x4*>(b1 + (size_t)e * HID_D + hc + hb);
#pragma unroll
        for (int nf = 0; nf < 2; ++nf) {
          int t = wt * 32 + nf * 16 + l15;
          u16 q0 = f2bf(fmaxf(accH[mf][nf][0] + bias[0], 0.f));
          u16 q1 = f2bf(fmaxf(accH[mf][nf][1] + bias[1], 0.f));
          u16 q2 = f2bf(fmaxf(accH[mf][nf][2] + bias[2], 0.f));
          u16 q3 = f2bf(fmaxf(accH[mf][nf][3] + bias[3], 0.f));
          unsigned int lo = (unsigned int)q0 | ((unsigned int)q1 << 16);
          unsigned int hi = (unsigned int)q2 | ((unsigned int)q3 << 16);
          int byte = t * 128 + ((hb * 2) ^ ((t & 7) << 4));
          *reinterpret_cast<u32x2*>(reinterpret_cast<char*>(Hs) + byte) = u32x2{lo, hi};
        }
      }
    }
    __syncthreads();

    // ---- phase 2: out^T += W2t_chunk @ H^T ----
#pragma unroll
    for (int kk = 0; kk < 2; ++kk) {
      bf16x8 a[4], b[4];
#pragma unroll
      for (int mf = 0; mf < 4; ++mf) {
        int o = wave * 64 + mf * 16 + l15;
        u32x4 v = *reinterpret_cast<const u32x4*>(
            w2t + ((size_t)(e * OUT_D + o)) * HID_D + hc + kk * 32 + l4 * 8);
        a[mf] = __builtin_bit_cast(bf16x8, v);
      }
#pragma unroll
      for (int nf = 0; nf < 4; ++nf) {
        int t = nf * 16 + l15;
        int byte = t * 128 + (((kk * 32 + l4 * 8) * 2) ^ ((t & 7) << 4));
        u32x4 v = *reinterpret_cast<const u32x4*>(reinterpret_cast<const char*>(Hs) + byte);
        b[nf] = __builtin_bit_cast(bf16x8, v);
      }
#pragma unroll
      for (int mf = 0; mf < 4; ++mf)
#pragma unroll
        for (int nf = 0; nf < 4; ++nf)
          acc[mf][nf] = __builtin_amdgcn_mfma_f32_16x16x32_bf16(a[mf], b[nf], acc[mf][nf], 0, 0, 0);
    }
    __syncthreads();
  }

  // ---- epilogue: out[t][o] += w * (acc + b2) ----
#pragma unroll
  for (int mf = 0; mf < 4; ++mf) {
    int ob = wave * 64 + mf * 16 + l4 * 4;
    f32x4 bv = *reinterpret_cast<const f32x4*>(b2 + (size_t)e * OUT_D + ob);
#pragma unroll
    for (int nf = 0; nf < 4; ++nf) {
      int trow = nf * 16 + l15;
      if (base + trow < cnt) {
        float w = gw[trow];
        float* dst = out + (size_t)toks[trow] * OUT_D + ob;
#pragma unroll
        for (int r = 0; r < 4; ++r)
          atomicAdd(dst + r, w * (acc[mf][nf][r] + bv[r]));
      }
    }
  }
}

// ---------------- launch ----------------
extern "C" void kernel_launch(void* const* d_in, const int* in_sizes, int n_in,
                              void* d_out, int out_size, void* d_ws, size_t ws_size,
                              hipStream_t stream) {
  const float* x  = (const float*)d_in[0];
  const float* Wg = (const float*)d_in[1];
  const float* W1 = (const float*)d_in[2];
  const float* b1 = (const float*)d_in[3];
  const float* W2 = (const float*)d_in[4];
  const float* b2 = (const float*)d_in[5];
  float* out = (float*)d_out;

  char* ws = (char*)d_ws;
  constexpr size_t OFF_XBF  = 0;                               // T*IN bf16 = 16 MB
  constexpr size_t OFF_W1T  = (size_t)T_TOK * IN_D * 2;        // 16777216
  constexpr size_t OFF_W2T  = OFF_W1T + (size_t)NE * HID_D * IN_D * 2;   // +4 MB
  constexpr size_t OFF_CNT  = OFF_W2T + (size_t)NE * OUT_D * HID_D * 2;  // +4 MB
  constexpr size_t OFF_LTOK = OFF_CNT + 128;
  constexpr size_t OFF_LW   = OFF_LTOK + (size_t)NE * T_TOK * 4;

  u16*   xbf      = (u16*)(ws + OFF_XBF);
  u16*   w1t      = (u16*)(ws + OFF_W1T);
  u16*   w2t      = (u16*)(ws + OFF_W2T);
  int*   counts   = (int*)(ws + OFF_CNT);
  int*   list_tok = (int*)(ws + OFF_LTOK);
  float* list_w   = (float*)(ws + OFF_LW);
  float* probs    = out + (size_t)T_TOK * OUT_D;

  hipMemsetAsync(d_out, 0, (size_t)out_size * sizeof(float), stream);
  hipMemsetAsync(counts, 0, NE * sizeof(int), stream);

  cvt_x_kernel<<<(T_TOK * IN_D / 4) / 256, 256, 0, stream>>>(x, xbf);
  cvt_w1_kernel<<<(NE * HID_D * IN_D) / 256, 256, 0, stream>>>(W1, w1t);
  cvt_w2_kernel<<<(NE * OUT_D * HID_D) / 256, 256, 0, stream>>>(W2, w2t);
  router_kernel<<<T_TOK / 256, 256, 0, stream>>>(x, Wg, probs, counts, list_tok, list_w);

  dim3 grid(T_TOK / BM, NE);  // 512 x 8; blocks past counts[e] exit immediately
  moe_main_kernel<<<grid, 256, 0, stream>>>(xbf, w1t, w2t, b1, b2, counts,
                                            list_tok, list_w, out);
}

// Round 2
// 536.253 us; speedup vs baseline: 1.3216x; 1.3216x over previous
//
#include <hip/hip_runtime.h>
#include <hip/hip_bf16.h>
#include <stdint.h>

#define T_TOK 32768
#define IN_D  256
#define HID_D 1024
#define OUT_D 256
#define NE    8
#define BM    64
#define HC    64

typedef unsigned short u16;
typedef __attribute__((ext_vector_type(8))) __bf16 bf16x8;
typedef __attribute__((ext_vector_type(4))) float f32x4;
typedef __attribute__((ext_vector_type(4))) unsigned int u32x4;
typedef __attribute__((ext_vector_type(2))) unsigned int u32x2;

__device__ __forceinline__ u16 f2bf(float f) {
  unsigned int u = __builtin_bit_cast(unsigned int, f);
  u = (u + 0x7FFFu + ((u >> 16) & 1u)) >> 16;
  return (u16)u;
}

// ---------------- x -> bf16 (coalesced) ----------------
__global__ __launch_bounds__(256) void cvt_x_kernel(const float* __restrict__ x,
                                                    u16* __restrict__ xbf) {
  int i = blockIdx.x * 256 + threadIdx.x;  // over T*IN/4
  f32x4 v = reinterpret_cast<const f32x4*>(x)[i];
  unsigned int lo = (unsigned int)f2bf(v[0]) | ((unsigned int)f2bf(v[1]) << 16);
  unsigned int hi = (unsigned int)f2bf(v[2]) | ((unsigned int)f2bf(v[3]) << 16);
  reinterpret_cast<u32x2*>(xbf)[i] = u32x2{lo, hi};
}

// ---------------- transpose-convert via LDS tile ----------------
// per-expert slab: in R x C (f32, row-major) -> out C x R (bf16, row-major).
// 64x64 tiles; both global read and write coalesced.
__global__ __launch_bounds__(256) void cvt_t_kernel(const float* __restrict__ in,
                                                    u16* __restrict__ outp,
                                                    int R, int C) {
  __shared__ float tile[64][65];
  int e = blockIdx.y;
  int nTR = R >> 6;
  int tR = (blockIdx.x % nTR) << 6;
  int tC = (blockIdx.x / nTR) << 6;
  const float* src = in + (size_t)e * R * C;
  u16* dst = outp + (size_t)e * R * C;
  int tid = threadIdx.x;
  int rr = tid >> 4;
  int cc = (tid & 15) * 4;
#pragma unroll
  for (int r0 = 0; r0 < 64; r0 += 16) {
    int r = r0 + rr;
    f32x4 v = *reinterpret_cast<const f32x4*>(src + (size_t)(tR + r) * C + tC + cc);
    tile[r][cc] = v[0]; tile[r][cc + 1] = v[1];
    tile[r][cc + 2] = v[2]; tile[r][cc + 3] = v[3];
  }
  __syncthreads();
  int cw = tid >> 4;
  int rw = (tid & 15) * 4;
#pragma unroll
  for (int c0 = 0; c0 < 64; c0 += 16) {
    int c = c0 + cw;
    u16 q0 = f2bf(tile[rw + 0][c]);
    u16 q1 = f2bf(tile[rw + 1][c]);
    u16 q2 = f2bf(tile[rw + 2][c]);
    u16 q3 = f2bf(tile[rw + 3][c]);
    unsigned int lo = (unsigned int)q0 | ((unsigned int)q1 << 16);
    unsigned int hi = (unsigned int)q2 | ((unsigned int)q3 << 16);
    *reinterpret_cast<u32x2*>(dst + (size_t)(tC + c) * R + tR + rw) = u32x2{lo, hi};
  }
}

// ---------------- router ----------------
// list_tok entry packs token | (slot<<16), slot 0 = top-1, 1 = top-2.
__global__ __launch_bounds__(256) void router_kernel(
    const float* __restrict__ x, const float* __restrict__ Wg,
    float* __restrict__ probs, int* __restrict__ counts,
    int* __restrict__ list_tok, float* __restrict__ list_w) {
  __shared__ float wg_s[IN_D * NE];
  int tid = threadIdx.x;
  for (int i = tid; i < IN_D * NE; i += 256) wg_s[i] = Wg[i];
  __syncthreads();

  int t = blockIdx.x * 256 + tid;
  float acc[NE];
#pragma unroll
  for (int e = 0; e < NE; ++e) acc[e] = 0.f;
  const f32x4* xr = reinterpret_cast<const f32x4*>(x + (size_t)t * IN_D);
  for (int i = 0; i < IN_D / 4; ++i) {
    f32x4 v = xr[i];
#pragma unroll
    for (int j = 0; j < 4; ++j) {
      float xv = v[j];
      const float* wrow = &wg_s[(i * 4 + j) * NE];
#pragma unroll
      for (int e = 0; e < NE; ++e) acc[e] += xv * wrow[e];
    }
  }
  float m = acc[0];
#pragma unroll
  for (int e = 1; e < NE; ++e) m = fmaxf(m, acc[e]);
  float p[NE], s = 0.f;
#pragma unroll
  for (int e = 0; e < NE; ++e) { p[e] = expf(acc[e] - m); s += p[e]; }
  float inv = 1.f / s;
#pragma unroll
  for (int e = 0; e < NE; ++e) {
    p[e] *= inv;
    probs[(size_t)t * NE + e] = p[e];
  }
  int i0 = 0; float p0 = p[0];
#pragma unroll
  for (int e = 1; e < NE; ++e) if (p[e] > p0) { p0 = p[e]; i0 = e; }
  int i1 = -1; float p1 = -1.f;
#pragma unroll
  for (int e = 0; e < NE; ++e) if (e != i0 && p[e] > p1) { p1 = p[e]; i1 = e; }
  float wsum = p0 + p1;

  int pos0 = atomicAdd(&counts[i0], 1);
  list_tok[(size_t)i0 * T_TOK + pos0] = t;              // slot 0
  list_w[(size_t)i0 * T_TOK + pos0] = p0 / wsum;
  int pos1 = atomicAdd(&counts[i1], 1);
  list_tok[(size_t)i1 * T_TOK + pos1] = t | (1 << 16);  // slot 1
  list_w[(size_t)i1 * T_TOK + pos1] = p1 / wsum;
}

// ---------------- fused expert FFN ----------------
// Flat grid: e = blockIdx.x & 7 (expert->XCD affinity), tile = blockIdx.x >> 3.
// Pipeline: phase1(c+1) -> Hs[(c+1)&1] overlaps phase2(c) <- Hs[c&1];
// one barrier per H-chunk. Epilogue: plain f32x4 stores to part[slot][tok][:].
__global__ __launch_bounds__(256, 3) void moe_main_kernel(
    const u16* __restrict__ xbf, const u16* __restrict__ w1t,
    const u16* __restrict__ w2t, const float* __restrict__ b1,
    const float* __restrict__ b2, const int* __restrict__ counts,
    const int* __restrict__ list_tok, const float* __restrict__ list_w,
    float* __restrict__ part) {
  int e = blockIdx.x & 7;
  int tile = blockIdx.x >> 3;
  int cnt = counts[e];
  int base = tile * BM;
  if (base >= cnt) return;

  __shared__ __align__(16) u16 Xs[BM * IN_D];     // 32 KB, swizzled 512B rows
  __shared__ __align__(16) u16 Hs[2][BM * HC];    // 16 KB, swizzled 128B rows
  __shared__ int toks[BM];
  __shared__ float gw[BM];

  int tid = threadIdx.x;
  int wave = tid >> 6;
  int lane = tid & 63;
  const int l15 = lane & 15;
  const int l4 = lane >> 4;

  if (tid < BM) {
    int idx = base + tid;
    int tv = 0; float w = 0.f;
    if (idx < cnt) { tv = list_tok[(size_t)e * T_TOK + idx]; w = list_w[(size_t)e * T_TOK + idx]; }
    toks[tid] = tv;
    gw[tid] = w;
  }
  __syncthreads();

  // stage gathered X rows (swizzled)
  {
    int half = lane >> 5;
    int c16 = lane & 31;
#pragma unroll
    for (int rr = 0; rr < 16; rr += 2) {
      int r = wave * 16 + rr + half;
      int t = toks[r] & 0xFFFF;
      u32x4 v = *reinterpret_cast<const u32x4*>(xbf + (size_t)t * IN_D + c16 * 8);
      int byte = r * 512 + ((c16 * 16) ^ ((r & 7) << 4));
      *reinterpret_cast<u32x4*>(reinterpret_cast<char*>(Xs) + byte) = v;
    }
  }
  __syncthreads();

  const int wh = wave >> 1;
  const int wt = wave & 1;

  // phase1: H chunk (64 h) for chunk index c -> Hs[buf]
  auto phase1 = [&](int c, int buf) {
    int hc = c * HC;
    f32x4 accH[2][2];
#pragma unroll
    for (int mf = 0; mf < 2; ++mf)
#pragma unroll
      for (int nf = 0; nf < 2; ++nf) accH[mf][nf] = f32x4{0.f, 0.f, 0.f, 0.f};
#pragma unroll
    for (int kk = 0; kk < 8; ++kk) {
      bf16x8 a[2], b[2];
#pragma unroll
      for (int mf = 0; mf < 2; ++mf) {
        int h = hc + wh * 32 + mf * 16 + l15;
        u32x4 v = *reinterpret_cast<const u32x4*>(
            w1t + ((size_t)(e * HID_D + h)) * IN_D + kk * 32 + l4 * 8);
        a[mf] = __builtin_bit_cast(bf16x8, v);
      }
#pragma unroll
      for (int nf = 0; nf < 2; ++nf) {
        int t = wt * 32 + nf * 16 + l15;
        int byte = t * 512 + (((kk * 32 + l4 * 8) * 2) ^ ((t & 7) << 4));
        u32x4 v = *reinterpret_cast<const u32x4*>(reinterpret_cast<const char*>(Xs) + byte);
        b[nf] = __builtin_bit_cast(bf16x8, v);
      }
#pragma unroll
      for (int mf = 0; mf < 2; ++mf)
#pragma unroll
        for (int nf = 0; nf < 2; ++nf)
          accH[mf][nf] = __builtin_amdgcn_mfma_f32_16x16x32_bf16(a[mf], b[nf], accH[mf][nf], 0, 0, 0);
    }
#pragma unroll
    for (int mf = 0; mf < 2; ++mf) {
      int hb = wh * 32 + mf * 16 + l4 * 4;
      f32x4 bias = *reinterpret_cast<const f32x4*>(b1 + (size_t)e * HID_D + hc + hb);
#pragma unroll
      for (int nf = 0; nf < 2; ++nf) {
        int t = wt * 32 + nf * 16 + l15;
        u16 q0 = f2bf(fmaxf(accH[mf][nf][0] + bias[0], 0.f));
        u16 q1 = f2bf(fmaxf(accH[mf][nf][1] + bias[1], 0.f));
        u16 q2 = f2bf(fmaxf(accH[mf][nf][2] + bias[2], 0.f));
        u16 q3 = f2bf(fmaxf(accH[mf][nf][3] + bias[3], 0.f));
        unsigned int lo = (unsigned int)q0 | ((unsigned int)q1 << 16);
        unsigned int hi = (unsigned int)q2 | ((unsigned int)q3 << 16);
        int byte = buf * (BM * HC * 2) + t * 128 + ((hb * 2) ^ ((t & 7) << 4));
        *reinterpret_cast<u32x2*>(reinterpret_cast<char*>(&Hs[0][0]) + byte) = u32x2{lo, hi};
      }
    }
  };

  // phase2: out^T += W2t chunk @ Hs[buf]
  f32x4 acc[4][4];
#pragma unroll
  for (int a = 0; a < 4; ++a)
#pragma unroll
    for (int b = 0; b < 4; ++b) acc[a][b] = f32x4{0.f, 0.f, 0.f, 0.f};

  auto phase2 = [&](int c, int buf) {
    int hc = c * HC;
#pragma unroll
    for (int kk = 0; kk < 2; ++kk) {
      bf16x8 a[4], b[4];
#pragma unroll
      for (int mf = 0; mf < 4; ++mf) {
        int o = wave * 64 + mf * 16 + l15;
        u32x4 v = *reinterpret_cast<const u32x4*>(
            w2t + ((size_t)(e * OUT_D + o)) * HID_D + hc + kk * 32 + l4 * 8);
        a[mf] = __builtin_bit_cast(bf16x8, v);
      }
#pragma unroll
      for (int nf = 0; nf < 4; ++nf) {
        int t = nf * 16 + l15;
        int byte = buf * (BM * HC * 2) + t * 128 + (((kk * 32 + l4 * 8) * 2) ^ ((t & 7) << 4));
        u32x4 v = *reinterpret_cast<const u32x4*>(reinterpret_cast<const char*>(&Hs[0][0]) + byte);
        b[nf] = __builtin_bit_cast(bf16x8, v);
      }
#pragma unroll
      for (int mf = 0; mf < 4; ++mf)
#pragma unroll
        for (int nf = 0; nf < 4; ++nf)
          acc[mf][nf] = __builtin_amdgcn_mfma_f32_16x16x32_bf16(a[mf], b[nf], acc[mf][nf], 0, 0, 0);
    }
  };

  phase1(0, 0);
  __syncthreads();
#pragma unroll 1
  for (int c = 0; c < HID_D / HC - 1; ++c) {
    phase2(c, c & 1);
    phase1(c + 1, (c + 1) & 1);
    __syncthreads();
  }
  phase2(HID_D / HC - 1, (HID_D / HC - 1) & 1);

  // epilogue: part[slot][tok][o] = w * (acc + b2)   (plain stores, no atomics)
#pragma unroll
  for (int mf = 0; mf < 4; ++mf) {
    int ob = wave * 64 + mf * 16 + l4 * 4;
    f32x4 bv = *reinterpret_cast<const f32x4*>(b2 + (size_t)e * OUT_D + ob);
#pragma unroll
    for (int nf = 0; nf < 4; ++nf) {
      int trow = nf * 16 + l15;
      if (base + trow < cnt) {
        int tv = toks[trow];
        int tok = tv & 0xFFFF;
        int slot = tv >> 16;
        float w = gw[trow];
        f32x4 o;
#pragma unroll
        for (int r = 0; r < 4; ++r) o[r] = w * (acc[mf][nf][r] + bv[r]);
        *reinterpret_cast<f32x4*>(part + ((size_t)slot * T_TOK + tok) * OUT_D + ob) = o;
      }
    }
  }
}

// ---------------- combine: out = part0 + part1 ----------------
__global__ __launch_bounds__(256) void combine_kernel(const float* __restrict__ part,
                                                      float* __restrict__ out) {
  size_t i = (size_t)blockIdx.x * 256 + threadIdx.x;  // over T*OUT/4
  f32x4 a = reinterpret_cast<const f32x4*>(part)[i];
  f32x4 b = reinterpret_cast<const f32x4*>(part + (size_t)T_TOK * OUT_D)[i];
  reinterpret_cast<f32x4*>(out)[i] = a + b;
}

// ---------------- launch ----------------
extern "C" void kernel_launch(void* const* d_in, const int* in_sizes, int n_in,
                              void* d_out, int out_size, void* d_ws, size_t ws_size,
                              hipStream_t stream) {
  const float* x  = (const float*)d_in[0];
  const float* Wg = (const float*)d_in[1];
  const float* W1 = (const float*)d_in[2];
  const float* b1 = (const float*)d_in[3];
  const float* W2 = (const float*)d_in[4];
  const float* b2 = (const float*)d_in[5];
  float* out = (float*)d_out;

  char* ws = (char*)d_ws;
  constexpr size_t OFF_XBF  = 0;
  constexpr size_t OFF_W1T  = (size_t)T_TOK * IN_D * 2;                   // 16 MB
  constexpr size_t OFF_W2T  = OFF_W1T + (size_t)NE * HID_D * IN_D * 2;    // +4 MB
  constexpr size_t OFF_CNT  = OFF_W2T + (size_t)NE * OUT_D * HID_D * 2;   // +4 MB
  constexpr size_t OFF_LTOK = OFF_CNT + 128;
  constexpr size_t OFF_LW   = OFF_LTOK + (size_t)NE * T_TOK * 4;          // +1 MB
  constexpr size_t OFF_PART = OFF_LW + (size_t)NE * T_TOK * 4;            // +1 MB
  // part: 2 * T_TOK * OUT_D * 4 = 64 MB ; total ~90 MB of ws

  u16*   xbf      = (u16*)(ws + OFF_XBF);
  u16*   w1t      = (u16*)(ws + OFF_W1T);
  u16*   w2t      = (u16*)(ws + OFF_W2T);
  int*   counts   = (int*)(ws + OFF_CNT);
  int*   list_tok = (int*)(ws + OFF_LTOK);
  float* list_w   = (float*)(ws + OFF_LW);
  float* part     = (float*)(ws + OFF_PART);
  float* probs    = out + (size_t)T_TOK * OUT_D;

  hipMemsetAsync(counts, 0, NE * sizeof(int), stream);

  cvt_x_kernel<<<(T_TOK * IN_D / 4) / 256, 256, 0, stream>>>(x, xbf);
  {
    dim3 g((IN_D / 64) * (HID_D / 64), NE);
    cvt_t_kernel<<<g, 256, 0, stream>>>(W1, w1t, IN_D, HID_D);
  }
  {
    dim3 g((HID_D / 64) * (OUT_D / 64), NE);
    cvt_t_kernel<<<g, 256, 0, stream>>>(W2, w2t, HID_D, OUT_D);
  }
  router_kernel<<<T_TOK / 256, 256, 0, stream>>>(x, Wg, probs, counts, list_tok, list_w);

  moe_main_kernel<<<(T_TOK / BM) * NE, 256, 0, stream>>>(
      xbf, w1t, w2t, b1, b2, counts, list_tok, list_w, part);

  combine_kernel<<<(T_TOK * OUT_D / 4) / 256, 256, 0, stream>>>(part, out);
}

// Round 3
// 333.796 us; speedup vs baseline: 2.1232x; 1.6065x over previous
//
#include <hip/hip_runtime.h>
#include <hip/hip_bf16.h>
#include <stdint.h>

#define T_TOK 32768
#define IN_D  256
#define HID_D 1024
#define OUT_D 256
#define NE    8
#define BM    64
#define HC    64

typedef unsigned short u16;
typedef __attribute__((ext_vector_type(8))) __bf16 bf16x8;
typedef __attribute__((ext_vector_type(4))) float f32x4;
typedef __attribute__((ext_vector_type(4))) unsigned int u32x4;
typedef __attribute__((ext_vector_type(2))) unsigned int u32x2;

__device__ __forceinline__ u16 f2bf(float f) {
  unsigned int u = __builtin_bit_cast(unsigned int, f);
  u = (u + 0x7FFFu + ((u >> 16) & 1u)) >> 16;
  return (u16)u;
}

// ---------------- transpose-convert via LDS tile ----------------
__global__ __launch_bounds__(256) void cvt_t_kernel(const float* __restrict__ in,
                                                    u16* __restrict__ outp,
                                                    int R, int C) {
  __shared__ float tile[64][65];
  int e = blockIdx.y;
  int nTR = R >> 6;
  int tR = (blockIdx.x % nTR) << 6;
  int tC = (blockIdx.x / nTR) << 6;
  const float* src = in + (size_t)e * R * C;
  u16* dst = outp + (size_t)e * R * C;
  int tid = threadIdx.x;
  int rr = tid >> 4;
  int cc = (tid & 15) * 4;
#pragma unroll
  for (int r0 = 0; r0 < 64; r0 += 16) {
    int r = r0 + rr;
    f32x4 v = *reinterpret_cast<const f32x4*>(src + (size_t)(tR + r) * C + tC + cc);
    tile[r][cc] = v[0]; tile[r][cc + 1] = v[1];
    tile[r][cc + 2] = v[2]; tile[r][cc + 3] = v[3];
  }
  __syncthreads();
  int cw = tid >> 4;
  int rw = (tid & 15) * 4;
#pragma unroll
  for (int c0 = 0; c0 < 64; c0 += 16) {
    int c = c0 + cw;
    u16 q0 = f2bf(tile[rw + 0][c]);
    u16 q1 = f2bf(tile[rw + 1][c]);
    u16 q2 = f2bf(tile[rw + 2][c]);
    u16 q3 = f2bf(tile[rw + 3][c]);
    unsigned int lo = (unsigned int)q0 | ((unsigned int)q1 << 16);
    unsigned int hi = (unsigned int)q2 | ((unsigned int)q3 << 16);
    *reinterpret_cast<u32x2*>(dst + (size_t)(tC + c) * R + tR + rw) = u32x2{lo, hi};
  }
}

// ---------------- router (coalesced, LDS-aggregated counts, fused x->bf16) ----
// 512 blocks x 256 thr; wave = 16 tokens, 4 lanes per token (quarter rows).
__global__ __launch_bounds__(256) void router_kernel(
    const float* __restrict__ x, const float* __restrict__ Wg,
    u16* __restrict__ xbf, float* __restrict__ probs, int* __restrict__ counts,
    int* __restrict__ list_tok, float* __restrict__ list_w) {
  __shared__ float wg_s[IN_D * NE];  // 8 KB [i][e]
  __shared__ int lcnt[NE];
  __shared__ int gbase[NE];
  int tid = threadIdx.x;
  for (int i = tid; i < IN_D * NE; i += 256) wg_s[i] = Wg[i];
  if (tid < NE) lcnt[tid] = 0;
  __syncthreads();

  int lane = tid & 63;
  int wave = tid >> 6;
  int q = lane & 3;                              // quarter-row group
  int tk = blockIdx.x * 64 + wave * 16 + (lane >> 2);

  float acc[NE];
#pragma unroll
  for (int e = 0; e < NE; ++e) acc[e] = 0.f;
  const float* xrow = x + (size_t)tk * IN_D;
  u16* xbrow = xbf + (size_t)tk * IN_D;
#pragma unroll
  for (int i = 0; i < 16; ++i) {
    int c = i * 4 + q;                           // 16B chunk index 0..63
    f32x4 v = *reinterpret_cast<const f32x4*>(xrow + c * 4);
    unsigned int lo = (unsigned int)f2bf(v[0]) | ((unsigned int)f2bf(v[1]) << 16);
    unsigned int hi = (unsigned int)f2bf(v[2]) | ((unsigned int)f2bf(v[3]) << 16);
    *reinterpret_cast<u32x2*>(xbrow + c * 4) = u32x2{lo, hi};
#pragma unroll
    for (int j = 0; j < 4; ++j) {
      const float* wr = &wg_s[(c * 4 + j) * NE];
#pragma unroll
      for (int e = 0; e < NE; ++e) acc[e] = fmaf(v[j], wr[e], acc[e]);
    }
  }
  // reduce quarter-row partials across the 4-lane group
#pragma unroll
  for (int e = 0; e < NE; ++e) {
    acc[e] += __shfl_xor(acc[e], 1);
    acc[e] += __shfl_xor(acc[e], 2);
  }
  // softmax (fp32)
  float m = acc[0];
#pragma unroll
  for (int e = 1; e < NE; ++e) m = fmaxf(m, acc[e]);
  float p[NE], s = 0.f;
#pragma unroll
  for (int e = 0; e < NE; ++e) { p[e] = expf(acc[e] - m); s += p[e]; }
  float inv = 1.f / s;
#pragma unroll
  for (int e = 0; e < NE; ++e) p[e] *= inv;
  // top-2, first-occurrence tie-break
  int i0 = 0; float p0 = p[0];
#pragma unroll
  for (int e = 1; e < NE; ++e) if (p[e] > p0) { p0 = p[e]; i0 = e; }
  int i1 = -1; float p1 = -1.f;
#pragma unroll
  for (int e = 0; e < NE; ++e) if (e != i0 && p[e] > p1) { p1 = p[e]; i1 = e; }
  float wsum = p0 + p1;

  int lp0 = 0, lp1 = 0;
  if (q == 0) {
    *reinterpret_cast<f32x4*>(probs + (size_t)tk * NE)     = f32x4{p[0], p[1], p[2], p[3]};
    *reinterpret_cast<f32x4*>(probs + (size_t)tk * NE + 4) = f32x4{p[4], p[5], p[6], p[7]};
    lp0 = atomicAdd(&lcnt[i0], 1);
    lp1 = atomicAdd(&lcnt[i1], 1);
  }
  __syncthreads();
  if (tid < NE) gbase[tid] = atomicAdd(&counts[tid], lcnt[tid]);
  __syncthreads();
  if (q == 0) {
    int e0 = gbase[i0] + lp0;
    list_tok[(size_t)i0 * T_TOK + e0] = tk;               // slot 0
    list_w[(size_t)i0 * T_TOK + e0] = p0 / wsum;
    int e1 = gbase[i1] + lp1;
    list_tok[(size_t)i1 * T_TOK + e1] = tk | (1 << 16);   // slot 1
    list_w[(size_t)i1 * T_TOK + e1] = p1 / wsum;
  }
}

// ---------------- fused expert FFN ----------------
__global__ __launch_bounds__(256, 3) void moe_main_kernel(
    const u16* __restrict__ xbf, const u16* __restrict__ w1t,
    const u16* __restrict__ w2t, const float* __restrict__ b1,
    const float* __restrict__ b2, const int* __restrict__ counts,
    const int* __restrict__ list_tok, const float* __restrict__ list_w,
    float* __restrict__ part) {
  int e = blockIdx.x & 7;
  int tile = blockIdx.x >> 3;
  int cnt = counts[e];
  int base = tile * BM;
  if (base >= cnt) return;

  __shared__ __align__(16) u16 Xs[BM * IN_D];     // 32 KB swizzled 512B rows
  __shared__ __align__(16) u16 Hs[2][BM * HC];    // 16 KB swizzled 128B rows
  __shared__ int toks[BM];
  __shared__ float gw[BM];

  int tid = threadIdx.x;
  int wave = tid >> 6;
  int lane = tid & 63;
  const int l15 = lane & 15;
  const int l4 = lane >> 4;

  if (tid < BM) {
    int idx = base + tid;
    int tv = 0; float w = 0.f;
    if (idx < cnt) { tv = list_tok[(size_t)e * T_TOK + idx]; w = list_w[(size_t)e * T_TOK + idx]; }
    toks[tid] = tv;
    gw[tid] = w;
  }
  __syncthreads();

  // stage gathered X rows (swizzled)
  {
    int half = lane >> 5;
    int c16 = lane & 31;
#pragma unroll
    for (int rr = 0; rr < 16; rr += 2) {
      int r = wave * 16 + rr + half;
      int t = toks[r] & 0xFFFF;
      u32x4 v = *reinterpret_cast<const u32x4*>(xbf + (size_t)t * IN_D + c16 * 8);
      int byte = r * 512 + ((c16 * 16) ^ ((r & 7) << 4));
      *reinterpret_cast<u32x4*>(reinterpret_cast<char*>(Xs) + byte) = v;
    }
  }
  __syncthreads();

  const int wh = wave >> 1;
  const int wt = wave & 1;

  // hoist chunk-invariant X B-fragments into registers (64 VGPR)
  bf16x8 bx[2][8];
#pragma unroll
  for (int nf = 0; nf < 2; ++nf)
#pragma unroll
    for (int kk = 0; kk < 8; ++kk) {
      int t = wt * 32 + nf * 16 + l15;
      int byte = t * 512 + (((kk * 32 + l4 * 8) * 2) ^ ((t & 7) << 4));
      bx[nf][kk] = __builtin_bit_cast(bf16x8,
          *reinterpret_cast<const u32x4*>(reinterpret_cast<const char*>(Xs) + byte));
    }

  auto phase1 = [&](int c, int buf) {
    int hc = c * HC;
    f32x4 accH[2][2];
#pragma unroll
    for (int mf = 0; mf < 2; ++mf)
#pragma unroll
      for (int nf = 0; nf < 2; ++nf) accH[mf][nf] = f32x4{0.f, 0.f, 0.f, 0.f};
#pragma unroll
    for (int kk = 0; kk < 8; ++kk) {
      bf16x8 a[2];
#pragma unroll
      for (int mf = 0; mf < 2; ++mf) {
        int h = hc + wh * 32 + mf * 16 + l15;
        u32x4 v = *reinterpret_cast<const u32x4*>(
            w1t + ((size_t)(e * HID_D + h)) * IN_D + kk * 32 + l4 * 8);
        a[mf] = __builtin_bit_cast(bf16x8, v);
      }
      __builtin_amdgcn_s_setprio(1);
#pragma unroll
      for (int mf = 0; mf < 2; ++mf)
#pragma unroll
        for (int nf = 0; nf < 2; ++nf)
          accH[mf][nf] = __builtin_amdgcn_mfma_f32_16x16x32_bf16(a[mf], bx[nf][kk], accH[mf][nf], 0, 0, 0);
      __builtin_amdgcn_s_setprio(0);
    }
#pragma unroll
    for (int mf = 0; mf < 2; ++mf) {
      int hb = wh * 32 + mf * 16 + l4 * 4;
      f32x4 bias = *reinterpret_cast<const f32x4*>(b1 + (size_t)e * HID_D + hc + hb);
#pragma unroll
      for (int nf = 0; nf < 2; ++nf) {
        int t = wt * 32 + nf * 16 + l15;
        u16 q0 = f2bf(fmaxf(accH[mf][nf][0] + bias[0], 0.f));
        u16 q1 = f2bf(fmaxf(accH[mf][nf][1] + bias[1], 0.f));
        u16 q2 = f2bf(fmaxf(accH[mf][nf][2] + bias[2], 0.f));
        u16 q3 = f2bf(fmaxf(accH[mf][nf][3] + bias[3], 0.f));
        unsigned int lo = (unsigned int)q0 | ((unsigned int)q1 << 16);
        unsigned int hi = (unsigned int)q2 | ((unsigned int)q3 << 16);
        int byte = buf * (BM * HC * 2) + t * 128 + ((hb * 2) ^ ((t & 7) << 4));
        *reinterpret_cast<u32x2*>(reinterpret_cast<char*>(&Hs[0][0]) + byte) = u32x2{lo, hi};
      }
    }
  };

  f32x4 acc[4][4];
#pragma unroll
  for (int a = 0; a < 4; ++a)
#pragma unroll
    for (int b = 0; b < 4; ++b) acc[a][b] = f32x4{0.f, 0.f, 0.f, 0.f};

  auto phase2 = [&](int c, int buf) {
    int hc = c * HC;
#pragma unroll
    for (int kk = 0; kk < 2; ++kk) {
      bf16x8 a[4], b[4];
#pragma unroll
      for (int mf = 0; mf < 4; ++mf) {
        int o = wave * 64 + mf * 16 + l15;
        u32x4 v = *reinterpret_cast<const u32x4*>(
            w2t + ((size_t)(e * OUT_D + o)) * HID_D + hc + kk * 32 + l4 * 8);
        a[mf] = __builtin_bit_cast(bf16x8, v);
      }
#pragma unroll
      for (int nf = 0; nf < 4; ++nf) {
        int t = nf * 16 + l15;
        int byte = buf * (BM * HC * 2) + t * 128 + (((kk * 32 + l4 * 8) * 2) ^ ((t & 7) << 4));
        u32x4 v = *reinterpret_cast<const u32x4*>(reinterpret_cast<const char*>(&Hs[0][0]) + byte);
        b[nf] = __builtin_bit_cast(bf16x8, v);
      }
      __builtin_amdgcn_s_setprio(1);
#pragma unroll
      for (int mf = 0; mf < 4; ++mf)
#pragma unroll
        for (int nf = 0; nf < 4; ++nf)
          acc[mf][nf] = __builtin_amdgcn_mfma_f32_16x16x32_bf16(a[mf], b[nf], acc[mf][nf], 0, 0, 0);
      __builtin_amdgcn_s_setprio(0);
    }
  };

  phase1(0, 0);
  __syncthreads();
#pragma unroll 1
  for (int c = 0; c < HID_D / HC - 1; ++c) {
    phase2(c, c & 1);
    phase1(c + 1, (c + 1) & 1);
    __syncthreads();
  }
  phase2(HID_D / HC - 1, (HID_D / HC - 1) & 1);

  // epilogue: part[slot][tok][o] = w * (acc + b2)
#pragma unroll
  for (int mf = 0; mf < 4; ++mf) {
    int ob = wave * 64 + mf * 16 + l4 * 4;
    f32x4 bv = *reinterpret_cast<const f32x4*>(b2 + (size_t)e * OUT_D + ob);
#pragma unroll
    for (int nf = 0; nf < 4; ++nf) {
      int trow = nf * 16 + l15;
      if (base + trow < cnt) {
        int tv = toks[trow];
        int tok = tv & 0xFFFF;
        int slot = tv >> 16;
        float w = gw[trow];
        f32x4 o;
#pragma unroll
        for (int r = 0; r < 4; ++r) o[r] = w * (acc[mf][nf][r] + bv[r]);
        *reinterpret_cast<f32x4*>(part + ((size_t)slot * T_TOK + tok) * OUT_D + ob) = o;
      }
    }
  }
}

// ---------------- combine: out = part0 + part1 ----------------
__global__ __launch_bounds__(256) void combine_kernel(const float* __restrict__ part,
                                                      float* __restrict__ out) {
  size_t i = (size_t)blockIdx.x * 256 + threadIdx.x;
  f32x4 a = reinterpret_cast<const f32x4*>(part)[i];
  f32x4 b = reinterpret_cast<const f32x4*>(part + (size_t)T_TOK * OUT_D)[i];
  reinterpret_cast<f32x4*>(out)[i] = a + b;
}

// ---------------- launch ----------------
extern "C" void kernel_launch(void* const* d_in, const int* in_sizes, int n_in,
                              void* d_out, int out_size, void* d_ws, size_t ws_size,
                              hipStream_t stream) {
  const float* x  = (const float*)d_in[0];
  const float* Wg = (const float*)d_in[1];
  const float* W1 = (const float*)d_in[2];
  const float* b1 = (const float*)d_in[3];
  const float* W2 = (const float*)d_in[4];
  const float* b2 = (const float*)d_in[5];
  float* out = (float*)d_out;

  char* ws = (char*)d_ws;
  constexpr size_t OFF_XBF  = 0;
  constexpr size_t OFF_W1T  = (size_t)T_TOK * IN_D * 2;
  constexpr size_t OFF_W2T  = OFF_W1T + (size_t)NE * HID_D * IN_D * 2;
  constexpr size_t OFF_CNT  = OFF_W2T + (size_t)NE * OUT_D * HID_D * 2;
  constexpr size_t OFF_LTOK = OFF_CNT + 128;
  constexpr size_t OFF_LW   = OFF_LTOK + (size_t)NE * T_TOK * 4;
  constexpr size_t OFF_PART = OFF_LW + (size_t)NE * T_TOK * 4;

  u16*   xbf      = (u16*)(ws + OFF_XBF);
  u16*   w1t      = (u16*)(ws + OFF_W1T);
  u16*   w2t      = (u16*)(ws + OFF_W2T);
  int*   counts   = (int*)(ws + OFF_CNT);
  int*   list_tok = (int*)(ws + OFF_LTOK);
  float* list_w   = (float*)(ws + OFF_LW);
  float* part     = (float*)(ws + OFF_PART);
  float* probs    = out + (size_t)T_TOK * OUT_D;

  hipMemsetAsync(counts, 0, NE * sizeof(int), stream);

  {
    dim3 g((IN_D / 64) * (HID_D / 64), NE);
    cvt_t_kernel<<<g, 256, 0, stream>>>(W1, w1t, IN_D, HID_D);
  }
  {
    dim3 g((HID_D / 64) * (OUT_D / 64), NE);
    cvt_t_kernel<<<g, 256, 0, stream>>>(W2, w2t, HID_D, OUT_D);
  }
  router_kernel<<<T_TOK / 64, 256, 0, stream>>>(x, Wg, xbf, probs, counts,
                                                list_tok, list_w);

  moe_main_kernel<<<(T_TOK / BM) * NE, 256, 0, stream>>>(
      xbf, w1t, w2t, b1, b2, counts, list_tok, list_w, part);

  combine_kernel<<<(T_TOK * OUT_D / 4) / 256, 256, 0, stream>>>(part, out);
}

// Round 4
// 291.893 us; speedup vs baseline: 2.4280x; 1.1436x over previous
//
#include <hip/hip_runtime.h>
#include <hip/hip_bf16.h>
#include <stdint.h>

#define T_TOK 32768
#define IN_D  256
#define HID_D 1024
#define OUT_D 256
#define NE    8
#define BM    64
#define HC    64

typedef unsigned short u16;
typedef __attribute__((ext_vector_type(8))) __bf16 bf16x8;
typedef __attribute__((ext_vector_type(4))) float f32x4;
typedef __attribute__((ext_vector_type(4))) unsigned int u32x4;
typedef __attribute__((ext_vector_type(2))) unsigned int u32x2;

__device__ __forceinline__ u16 f2bf(float f) {
  unsigned int u = __builtin_bit_cast(unsigned int, f);
  u = (u + 0x7FFFu + ((u >> 16) & 1u)) >> 16;
  return (u16)u;
}

// ---------------- transpose-convert via LDS tile ----------------
__global__ __launch_bounds__(256) void cvt_t_kernel(const float* __restrict__ in,
                                                    u16* __restrict__ outp,
                                                    int R, int C) {
  __shared__ float tile[64][65];
  int e = blockIdx.y;
  int nTR = R >> 6;
  int tR = (blockIdx.x % nTR) << 6;
  int tC = (blockIdx.x / nTR) << 6;
  const float* src = in + (size_t)e * R * C;
  u16* dst = outp + (size_t)e * R * C;
  int tid = threadIdx.x;
  int rr = tid >> 4;
  int cc = (tid & 15) * 4;
#pragma unroll
  for (int r0 = 0; r0 < 64; r0 += 16) {
    int r = r0 + rr;
    f32x4 v = *reinterpret_cast<const f32x4*>(src + (size_t)(tR + r) * C + tC + cc);
    tile[r][cc] = v[0]; tile[r][cc + 1] = v[1];
    tile[r][cc + 2] = v[2]; tile[r][cc + 3] = v[3];
  }
  __syncthreads();
  int cw = tid >> 4;
  int rw = (tid & 15) * 4;
#pragma unroll
  for (int c0 = 0; c0 < 64; c0 += 16) {
    int c = c0 + cw;
    u16 q0 = f2bf(tile[rw + 0][c]);
    u16 q1 = f2bf(tile[rw + 1][c]);
    u16 q2 = f2bf(tile[rw + 2][c]);
    u16 q3 = f2bf(tile[rw + 3][c]);
    unsigned int lo = (unsigned int)q0 | ((unsigned int)q1 << 16);
    unsigned int hi = (unsigned int)q2 | ((unsigned int)q3 << 16);
    *reinterpret_cast<u32x2*>(dst + (size_t)(tC + c) * R + tR + rw) = u32x2{lo, hi};
  }
}

// ---------------- router (coalesced, LDS-aggregated counts, fused x->bf16) ----
__global__ __launch_bounds__(256) void router_kernel(
    const float* __restrict__ x, const float* __restrict__ Wg,
    u16* __restrict__ xbf, float* __restrict__ probs, int* __restrict__ counts,
    int* __restrict__ list_tok, float* __restrict__ list_w) {
  __shared__ float wg_s[IN_D * NE];
  __shared__ int lcnt[NE];
  __shared__ int gbase[NE];
  int tid = threadIdx.x;
  for (int i = tid; i < IN_D * NE; i += 256) wg_s[i] = Wg[i];
  if (tid < NE) lcnt[tid] = 0;
  __syncthreads();

  int lane = tid & 63;
  int wave = tid >> 6;
  int q = lane & 3;
  int tk = blockIdx.x * 64 + wave * 16 + (lane >> 2);

  float acc[NE];
#pragma unroll
  for (int e = 0; e < NE; ++e) acc[e] = 0.f;
  const float* xrow = x + (size_t)tk * IN_D;
  u16* xbrow = xbf + (size_t)tk * IN_D;
#pragma unroll
  for (int i = 0; i < 16; ++i) {
    int c = i * 4 + q;
    f32x4 v = *reinterpret_cast<const f32x4*>(xrow + c * 4);
    unsigned int lo = (unsigned int)f2bf(v[0]) | ((unsigned int)f2bf(v[1]) << 16);
    unsigned int hi = (unsigned int)f2bf(v[2]) | ((unsigned int)f2bf(v[3]) << 16);
    *reinterpret_cast<u32x2*>(xbrow + c * 4) = u32x2{lo, hi};
#pragma unroll
    for (int j = 0; j < 4; ++j) {
      const float* wr = &wg_s[(c * 4 + j) * NE];
#pragma unroll
      for (int e = 0; e < NE; ++e) acc[e] = fmaf(v[j], wr[e], acc[e]);
    }
  }
#pragma unroll
  for (int e = 0; e < NE; ++e) {
    acc[e] += __shfl_xor(acc[e], 1);
    acc[e] += __shfl_xor(acc[e], 2);
  }
  float m = acc[0];
#pragma unroll
  for (int e = 1; e < NE; ++e) m = fmaxf(m, acc[e]);
  float p[NE], s = 0.f;
#pragma unroll
  for (int e = 0; e < NE; ++e) { p[e] = expf(acc[e] - m); s += p[e]; }
  float inv = 1.f / s;
#pragma unroll
  for (int e = 0; e < NE; ++e) p[e] *= inv;
  int i0 = 0; float p0 = p[0];
#pragma unroll
  for (int e = 1; e < NE; ++e) if (p[e] > p0) { p0 = p[e]; i0 = e; }
  int i1 = -1; float p1 = -1.f;
#pragma unroll
  for (int e = 0; e < NE; ++e) if (e != i0 && p[e] > p1) { p1 = p[e]; i1 = e; }
  float wsum = p0 + p1;

  int lp0 = 0, lp1 = 0;
  if (q == 0) {
    *reinterpret_cast<f32x4*>(probs + (size_t)tk * NE)     = f32x4{p[0], p[1], p[2], p[3]};
    *reinterpret_cast<f32x4*>(probs + (size_t)tk * NE + 4) = f32x4{p[4], p[5], p[6], p[7]};
    lp0 = atomicAdd(&lcnt[i0], 1);
    lp1 = atomicAdd(&lcnt[i1], 1);
  }
  __syncthreads();
  if (tid < NE) gbase[tid] = atomicAdd(&counts[tid], lcnt[tid]);
  __syncthreads();
  if (q == 0) {
    int e0 = gbase[i0] + lp0;
    list_tok[(size_t)i0 * T_TOK + e0] = tk;
    list_w[(size_t)i0 * T_TOK + e0] = p0 / wsum;
    int e1 = gbase[i1] + lp1;
    list_tok[(size_t)i1 * T_TOK + e1] = tk | (1 << 16);
    list_w[(size_t)i1 * T_TOK + e1] = p1 / wsum;
  }
}

// ---------------- fused expert FFN ----------------
// Streaming traffic (X gather, part stores) is non-temporal so the expert's
// 1 MB of weights stays L2-resident; weight loads are plain per-wave loads
// the compiler can batch with the freed VGPR budget (no bx hoist).
__global__ __launch_bounds__(256, 3) void moe_main_kernel(
    const u16* __restrict__ xbf, const u16* __restrict__ w1t,
    const u16* __restrict__ w2t, const float* __restrict__ b1,
    const float* __restrict__ b2, const int* __restrict__ counts,
    const int* __restrict__ list_tok, const float* __restrict__ list_w,
    float* __restrict__ part) {
  int e = blockIdx.x & 7;
  int tile = blockIdx.x >> 3;
  int cnt = counts[e];
  int base = tile * BM;
  if (base >= cnt) return;

  __shared__ __align__(16) u16 Xs[BM * IN_D];     // 32 KB swizzled 512B rows
  __shared__ __align__(16) u16 Hs[2][BM * HC];    // 16 KB swizzled 128B rows
  __shared__ int toks[BM];
  __shared__ float gw[BM];

  int tid = threadIdx.x;
  int wave = tid >> 6;
  int lane = tid & 63;
  const int l15 = lane & 15;
  const int l4 = lane >> 4;

  if (tid < BM) {
    int idx = base + tid;
    int tv = 0; float w = 0.f;
    if (idx < cnt) { tv = list_tok[(size_t)e * T_TOK + idx]; w = list_w[(size_t)e * T_TOK + idx]; }
    toks[tid] = tv;
    gw[tid] = w;
  }
  __syncthreads();

  // stage gathered X rows (swizzled, non-temporal reads)
  {
    int half = lane >> 5;
    int c16 = lane & 31;
#pragma unroll
    for (int rr = 0; rr < 16; rr += 2) {
      int r = wave * 16 + rr + half;
      int t = toks[r] & 0xFFFF;
      u32x4 v = __builtin_nontemporal_load(
          reinterpret_cast<const u32x4*>(xbf + (size_t)t * IN_D + c16 * 8));
      int byte = r * 512 + ((c16 * 16) ^ ((r & 7) << 4));
      *reinterpret_cast<u32x4*>(reinterpret_cast<char*>(Xs) + byte) = v;
    }
  }
  __syncthreads();

  const int wh = wave >> 1;
  const int wt = wave & 1;

  auto phase1 = [&](int c, int buf) {
    int hc = c * HC;
    f32x4 accH[2][2];
#pragma unroll
    for (int mf = 0; mf < 2; ++mf)
#pragma unroll
      for (int nf = 0; nf < 2; ++nf) accH[mf][nf] = f32x4{0.f, 0.f, 0.f, 0.f};
#pragma unroll
    for (int kk = 0; kk < 8; ++kk) {
      bf16x8 a[2], b[2];
#pragma unroll
      for (int mf = 0; mf < 2; ++mf) {
        int h = hc + wh * 32 + mf * 16 + l15;
        u32x4 v = *reinterpret_cast<const u32x4*>(
            w1t + ((size_t)(e * HID_D + h)) * IN_D + kk * 32 + l4 * 8);
        a[mf] = __builtin_bit_cast(bf16x8, v);
      }
#pragma unroll
      for (int nf = 0; nf < 2; ++nf) {
        int t = wt * 32 + nf * 16 + l15;
        int byte = t * 512 + (((kk * 32 + l4 * 8) * 2) ^ ((t & 7) << 4));
        u32x4 v = *reinterpret_cast<const u32x4*>(reinterpret_cast<const char*>(Xs) + byte);
        b[nf] = __builtin_bit_cast(bf16x8, v);
      }
#pragma unroll
      for (int mf = 0; mf < 2; ++mf)
#pragma unroll
        for (int nf = 0; nf < 2; ++nf)
          accH[mf][nf] = __builtin_amdgcn_mfma_f32_16x16x32_bf16(a[mf], b[nf], accH[mf][nf], 0, 0, 0);
    }
#pragma unroll
    for (int mf = 0; mf < 2; ++mf) {
      int hb = wh * 32 + mf * 16 + l4 * 4;
      f32x4 bias = *reinterpret_cast<const f32x4*>(b1 + (size_t)e * HID_D + hc + hb);
#pragma unroll
      for (int nf = 0; nf < 2; ++nf) {
        int t = wt * 32 + nf * 16 + l15;
        u16 q0 = f2bf(fmaxf(accH[mf][nf][0] + bias[0], 0.f));
        u16 q1 = f2bf(fmaxf(accH[mf][nf][1] + bias[1], 0.f));
        u16 q2 = f2bf(fmaxf(accH[mf][nf][2] + bias[2], 0.f));
        u16 q3 = f2bf(fmaxf(accH[mf][nf][3] + bias[3], 0.f));
        unsigned int lo = (unsigned int)q0 | ((unsigned int)q1 << 16);
        unsigned int hi = (unsigned int)q2 | ((unsigned int)q3 << 16);
        int byte = buf * (BM * HC * 2) + t * 128 + ((hb * 2) ^ ((t & 7) << 4));
        *reinterpret_cast<u32x2*>(reinterpret_cast<char*>(&Hs[0][0]) + byte) = u32x2{lo, hi};
      }
    }
  };

  f32x4 acc[4][4];
#pragma unroll
  for (int a = 0; a < 4; ++a)
#pragma unroll
    for (int b = 0; b < 4; ++b) acc[a][b] = f32x4{0.f, 0.f, 0.f, 0.f};

  auto phase2 = [&](int c, int buf) {
    int hc = c * HC;
#pragma unroll
    for (int kk = 0; kk < 2; ++kk) {
      bf16x8 a[4], b[4];
#pragma unroll
      for (int mf = 0; mf < 4; ++mf) {
        int o = wave * 64 + mf * 16 + l15;
        u32x4 v = *reinterpret_cast<const u32x4*>(
            w2t + ((size_t)(e * OUT_D + o)) * HID_D + hc + kk * 32 + l4 * 8);
        a[mf] = __builtin_bit_cast(bf16x8, v);
      }
#pragma unroll
      for (int nf = 0; nf < 4; ++nf) {
        int t = nf * 16 + l15;
        int byte = buf * (BM * HC * 2) + t * 128 + (((kk * 32 + l4 * 8) * 2) ^ ((t & 7) << 4));
        u32x4 v = *reinterpret_cast<const u32x4*>(reinterpret_cast<const char*>(&Hs[0][0]) + byte);
        b[nf] = __builtin_bit_cast(bf16x8, v);
      }
#pragma unroll
      for (int mf = 0; mf < 4; ++mf)
#pragma unroll
        for (int nf = 0; nf < 4; ++nf)
          acc[mf][nf] = __builtin_amdgcn_mfma_f32_16x16x32_bf16(a[mf], b[nf], acc[mf][nf], 0, 0, 0);
    }
  };

  phase1(0, 0);
  __syncthreads();
#pragma unroll 1
  for (int c = 0; c < HID_D / HC - 1; ++c) {
    phase2(c, c & 1);
    phase1(c + 1, (c + 1) & 1);
    __syncthreads();
  }
  phase2(HID_D / HC - 1, (HID_D / HC - 1) & 1);

  // epilogue: part[slot][tok][o] = w * (acc + b2)  (non-temporal stores)
#pragma unroll
  for (int mf = 0; mf < 4; ++mf) {
    int ob = wave * 64 + mf * 16 + l4 * 4;
    f32x4 bv = *reinterpret_cast<const f32x4*>(b2 + (size_t)e * OUT_D + ob);
#pragma unroll
    for (int nf = 0; nf < 4; ++nf) {
      int trow = nf * 16 + l15;
      if (base + trow < cnt) {
        int tv = toks[trow];
        int tok = tv & 0xFFFF;
        int slot = tv >> 16;
        float w = gw[trow];
        f32x4 o;
#pragma unroll
        for (int r = 0; r < 4; ++r) o[r] = w * (acc[mf][nf][r] + bv[r]);
        __builtin_nontemporal_store(
            o, reinterpret_cast<f32x4*>(part + ((size_t)slot * T_TOK + tok) * OUT_D + ob));
      }
    }
  }
}

// ---------------- combine: out = part0 + part1 ----------------
__global__ __launch_bounds__(256) void combine_kernel(const float* __restrict__ part,
                                                      float* __restrict__ out) {
  size_t i = (size_t)blockIdx.x * 256 + threadIdx.x;
  f32x4 a = __builtin_nontemporal_load(reinterpret_cast<const f32x4*>(part) + i);
  f32x4 b = __builtin_nontemporal_load(
      reinterpret_cast<const f32x4*>(part + (size_t)T_TOK * OUT_D) + i);
  f32x4 o = a + b;
  __builtin_nontemporal_store(o, reinterpret_cast<f32x4*>(out) + i);
}

// ---------------- launch ----------------
extern "C" void kernel_launch(void* const* d_in, const int* in_sizes, int n_in,
                              void* d_out, int out_size, void* d_ws, size_t ws_size,
                              hipStream_t stream) {
  const float* x  = (const float*)d_in[0];
  const float* Wg = (const float*)d_in[1];
  const float* W1 = (const float*)d_in[2];
  const float* b1 = (const float*)d_in[3];
  const float* W2 = (const float*)d_in[4];
  const float* b2 = (const float*)d_in[5];
  float* out = (float*)d_out;

  char* ws = (char*)d_ws;
  constexpr size_t OFF_XBF  = 0;
  constexpr size_t OFF_W1T  = (size_t)T_TOK * IN_D * 2;
  constexpr size_t OFF_W2T  = OFF_W1T + (size_t)NE * HID_D * IN_D * 2;
  constexpr size_t OFF_CNT  = OFF_W2T + (size_t)NE * OUT_D * HID_D * 2;
  constexpr size_t OFF_LTOK = OFF_CNT + 128;
  constexpr size_t OFF_LW   = OFF_LTOK + (size_t)NE * T_TOK * 4;
  constexpr size_t OFF_PART = OFF_LW + (size_t)NE * T_TOK * 4;

  u16*   xbf      = (u16*)(ws + OFF_XBF);
  u16*   w1t      = (u16*)(ws + OFF_W1T);
  u16*   w2t      = (u16*)(ws + OFF_W2T);
  int*   counts   = (int*)(ws + OFF_CNT);
  int*   list_tok = (int*)(ws + OFF_LTOK);
  float* list_w   = (float*)(ws + OFF_LW);
  float* part     = (float*)(ws + OFF_PART);
  float* probs    = out + (size_t)T_TOK * OUT_D;

  hipMemsetAsync(counts, 0, NE * sizeof(int), stream);

  {
    dim3 g((IN_D / 64) * (HID_D / 64), NE);
    cvt_t_kernel<<<g, 256, 0, stream>>>(W1, w1t, IN_D, HID_D);
  }
  {
    dim3 g((HID_D / 64) * (OUT_D / 64), NE);
    cvt_t_kernel<<<g, 256, 0, stream>>>(W2, w2t, HID_D, OUT_D);
  }
  router_kernel<<<T_TOK / 64, 256, 0, stream>>>(x, Wg, xbf, probs, counts,
                                                list_tok, list_w);

  moe_main_kernel<<<(T_TOK / BM) * NE, 256, 0, stream>>>(
      xbf, w1t, w2t, b1, b2, counts, list_tok, list_w, part);

  combine_kernel<<<(T_TOK * OUT_D / 4) / 256, 256, 0, stream>>>(part, out);
}

// Round 5
// 216.996 us; speedup vs baseline: 3.2661x; 1.3452x over previous
//
#include <hip/hip_runtime.h>
#include <hip/hip_bf16.h>
#include <stdint.h>

#define T_TOK 32768
#define IN_D  256
#define HID_D 1024
#define OUT_D 256
#define NE    8
#define BM    64
#define HC    64
#define NCHUNK (HID_D / HC)   // 16

typedef unsigned short u16;
typedef __attribute__((ext_vector_type(8))) __bf16 bf16x8;
typedef __attribute__((ext_vector_type(4))) float f32x4;
typedef __attribute__((ext_vector_type(4))) unsigned int u32x4;
typedef __attribute__((ext_vector_type(2))) unsigned int u32x2;

__device__ __forceinline__ u16 f2bf(float f) {
  unsigned int u = __builtin_bit_cast(unsigned int, f);
  u = (u + 0x7FFFu + ((u >> 16) & 1u)) >> 16;
  return (u16)u;
}

// ---------------- transpose-convert via LDS tile ----------------
__global__ __launch_bounds__(256) void cvt_t_kernel(const float* __restrict__ in,
                                                    u16* __restrict__ outp,
                                                    int R, int C) {
  __shared__ float tile[64][65];
  int e = blockIdx.y;
  int nTR = R >> 6;
  int tR = (blockIdx.x % nTR) << 6;
  int tC = (blockIdx.x / nTR) << 6;
  const float* src = in + (size_t)e * R * C;
  u16* dst = outp + (size_t)e * R * C;
  int tid = threadIdx.x;
  int rr = tid >> 4;
  int cc = (tid & 15) * 4;
#pragma unroll
  for (int r0 = 0; r0 < 64; r0 += 16) {
    int r = r0 + rr;
    f32x4 v = *reinterpret_cast<const f32x4*>(src + (size_t)(tR + r) * C + tC + cc);
    tile[r][cc] = v[0]; tile[r][cc + 1] = v[1];
    tile[r][cc + 2] = v[2]; tile[r][cc + 3] = v[3];
  }
  __syncthreads();
  int cw = tid >> 4;
  int rw = (tid & 15) * 4;
#pragma unroll
  for (int c0 = 0; c0 < 64; c0 += 16) {
    int c = c0 + cw;
    u16 q0 = f2bf(tile[rw + 0][c]);
    u16 q1 = f2bf(tile[rw + 1][c]);
    u16 q2 = f2bf(tile[rw + 2][c]);
    u16 q3 = f2bf(tile[rw + 3][c]);
    unsigned int lo = (unsigned int)q0 | ((unsigned int)q1 << 16);
    unsigned int hi = (unsigned int)q2 | ((unsigned int)q3 << 16);
    *reinterpret_cast<u32x2*>(dst + (size_t)(tC + c) * R + tR + rw) = u32x2{lo, hi};
  }
}

// ---------------- router (coalesced, LDS-aggregated counts, fused x->bf16) ----
__global__ __launch_bounds__(256) void router_kernel(
    const float* __restrict__ x, const float* __restrict__ Wg,
    u16* __restrict__ xbf, float* __restrict__ probs, int* __restrict__ counts,
    int* __restrict__ list_tok, float* __restrict__ list_w) {
  __shared__ float wg_s[IN_D * NE];
  __shared__ int lcnt[NE];
  __shared__ int gbase[NE];
  int tid = threadIdx.x;
  for (int i = tid; i < IN_D * NE; i += 256) wg_s[i] = Wg[i];
  if (tid < NE) lcnt[tid] = 0;
  __syncthreads();

  int lane = tid & 63;
  int wave = tid >> 6;
  int q = lane & 3;
  int tk = blockIdx.x * 64 + wave * 16 + (lane >> 2);

  float acc[NE];
#pragma unroll
  for (int e = 0; e < NE; ++e) acc[e] = 0.f;
  const float* xrow = x + (size_t)tk * IN_D;
  u16* xbrow = xbf + (size_t)tk * IN_D;
#pragma unroll
  for (int i = 0; i < 16; ++i) {
    int c = i * 4 + q;
    f32x4 v = *reinterpret_cast<const f32x4*>(xrow + c * 4);
    unsigned int lo = (unsigned int)f2bf(v[0]) | ((unsigned int)f2bf(v[1]) << 16);
    unsigned int hi = (unsigned int)f2bf(v[2]) | ((unsigned int)f2bf(v[3]) << 16);
    *reinterpret_cast<u32x2*>(xbrow + c * 4) = u32x2{lo, hi};
#pragma unroll
    for (int j = 0; j < 4; ++j) {
      const float* wr = &wg_s[(c * 4 + j) * NE];
#pragma unroll
      for (int e = 0; e < NE; ++e) acc[e] = fmaf(v[j], wr[e], acc[e]);
    }
  }
#pragma unroll
  for (int e = 0; e < NE; ++e) {
    acc[e] += __shfl_xor(acc[e], 1);
    acc[e] += __shfl_xor(acc[e], 2);
  }
  float m = acc[0];
#pragma unroll
  for (int e = 1; e < NE; ++e) m = fmaxf(m, acc[e]);
  float p[NE], s = 0.f;
#pragma unroll
  for (int e = 0; e < NE; ++e) { p[e] = expf(acc[e] - m); s += p[e]; }
  float inv = 1.f / s;
#pragma unroll
  for (int e = 0; e < NE; ++e) p[e] *= inv;
  int i0 = 0; float p0 = p[0];
#pragma unroll
  for (int e = 1; e < NE; ++e) if (p[e] > p0) { p0 = p[e]; i0 = e; }
  int i1 = -1; float p1 = -1.f;
#pragma unroll
  for (int e = 0; e < NE; ++e) if (e != i0 && p[e] > p1) { p1 = p[e]; i1 = e; }
  float wsum = p0 + p1;

  int lp0 = 0, lp1 = 0;
  if (q == 0) {
    *reinterpret_cast<f32x4*>(probs + (size_t)tk * NE)     = f32x4{p[0], p[1], p[2], p[3]};
    *reinterpret_cast<f32x4*>(probs + (size_t)tk * NE + 4) = f32x4{p[4], p[5], p[6], p[7]};
    lp0 = atomicAdd(&lcnt[i0], 1);
    lp1 = atomicAdd(&lcnt[i1], 1);
  }
  __syncthreads();
  if (tid < NE) gbase[tid] = atomicAdd(&counts[tid], lcnt[tid]);
  __syncthreads();
  if (q == 0) {
    int e0 = gbase[i0] + lp0;
    list_tok[(size_t)i0 * T_TOK + e0] = tk;
    list_w[(size_t)i0 * T_TOK + e0] = p0 / wsum;
    int e1 = gbase[i1] + lp1;
    list_tok[(size_t)i1 * T_TOK + e1] = tk | (1 << 16);
    list_w[(size_t)i1 * T_TOK + e1] = p1 / wsum;
  }
}

// ---------------- fused expert FFN, register-pipelined weights ----------------
// Each wave owns 16 h-rows in phase1 (no duplicate W1 reads) and 64 o-rows in
// phase2. Weight fragments live in VGPRs (w1buf/w2buf) and are reloaded for
// chunk c+1 immediately after their last use in chunk c, so global-load
// latency overlaps a full chunk of MFMA+LDS work.
__global__ __launch_bounds__(256, 2) void moe_main_kernel(
    const u16* __restrict__ xbf, const u16* __restrict__ w1t,
    const u16* __restrict__ w2t, const float* __restrict__ b1,
    const float* __restrict__ b2, const int* __restrict__ counts,
    const int* __restrict__ list_tok, const float* __restrict__ list_w,
    float* __restrict__ part) {
  int e = blockIdx.x & 7;
  int tile = blockIdx.x >> 3;
  int cnt = counts[e];
  int base = tile * BM;
  if (base >= cnt) return;

  __shared__ __align__(16) u16 Xs[BM * IN_D];     // 32 KB swizzled 512B rows
  __shared__ __align__(16) u16 Hs[2][BM * HC];    // 16 KB swizzled 128B rows
  __shared__ int toks[BM];
  __shared__ float gw[BM];

  int tid = threadIdx.x;
  int wave = tid >> 6;
  int lane = tid & 63;
  const int l15 = lane & 15;
  const int l4 = lane >> 4;

  if (tid < BM) {
    int idx = base + tid;
    int tv = 0; float w = 0.f;
    if (idx < cnt) { tv = list_tok[(size_t)e * T_TOK + idx]; w = list_w[(size_t)e * T_TOK + idx]; }
    toks[tid] = tv;
    gw[tid] = w;
  }
  __syncthreads();

  // stage gathered X rows (swizzled, non-temporal)
  {
    int half = lane >> 5;
    int c16 = lane & 31;
#pragma unroll
    for (int rr = 0; rr < 16; rr += 2) {
      int r = wave * 16 + rr + half;
      int t = toks[r] & 0xFFFF;
      u32x4 v = __builtin_nontemporal_load(
          reinterpret_cast<const u32x4*>(xbf + (size_t)t * IN_D + c16 * 8));
      int byte = r * 512 + ((c16 * 16) ^ ((r & 7) << 4));
      *reinterpret_cast<u32x4*>(reinterpret_cast<char*>(Xs) + byte) = v;
    }
  }

  // per-lane weight base pointers
  const u16* w1p = w1t + ((size_t)(e * HID_D + wave * 16 + l15)) * IN_D + l4 * 8;
  const u16* w2p = w2t + ((size_t)(e * OUT_D + wave * 64 + l15)) * HID_D + l4 * 8;

  u32x4 w1buf[8];   // phase1 A-frags for one chunk: [kk]
  u32x4 w2buf[8];   // phase2 A-frags for one chunk: [mf*2+kk]

  auto loadW1 = [&](int c) {
    const u16* p = w1p + (size_t)c * HC * IN_D;
#pragma unroll
    for (int kk = 0; kk < 8; ++kk)
      w1buf[kk] = *reinterpret_cast<const u32x4*>(p + kk * 32);
  };
  auto loadW2 = [&](int c) {
    const u16* p = w2p + c * HC;
#pragma unroll
    for (int mf = 0; mf < 4; ++mf)
#pragma unroll
      for (int kk = 0; kk < 2; ++kk)
        w2buf[mf * 2 + kk] = *reinterpret_cast<const u32x4*>(
            p + (size_t)mf * 16 * HID_D + kk * 32);
  };

  loadW1(0);
  loadW2(0);
  __syncthreads();  // Xs ready

  // phase1: compute H chunk c into Hs[buf] using w1buf (wave owns 16 h-rows)
  auto phase1 = [&](int c, int buf) {
    f32x4 accH[4];
#pragma unroll
    for (int nf = 0; nf < 4; ++nf) accH[nf] = f32x4{0.f, 0.f, 0.f, 0.f};
#pragma unroll
    for (int kk = 0; kk < 8; ++kk) {
      bf16x8 a = __builtin_bit_cast(bf16x8, w1buf[kk]);
#pragma unroll
      for (int nf = 0; nf < 4; ++nf) {
        int t = nf * 16 + l15;
        int byte = t * 512 + (((kk * 32 + l4 * 8) * 2) ^ ((t & 7) << 4));
        bf16x8 b = __builtin_bit_cast(bf16x8,
            *reinterpret_cast<const u32x4*>(reinterpret_cast<const char*>(Xs) + byte));
        accH[nf] = __builtin_amdgcn_mfma_f32_16x16x32_bf16(a, b, accH[nf], 0, 0, 0);
      }
    }
    int hb = wave * 16 + l4 * 4;
    f32x4 bias = *reinterpret_cast<const f32x4*>(b1 + (size_t)e * HID_D + c * HC + hb);
#pragma unroll
    for (int nf = 0; nf < 4; ++nf) {
      int t = nf * 16 + l15;
      u16 q0 = f2bf(fmaxf(accH[nf][0] + bias[0], 0.f));
      u16 q1 = f2bf(fmaxf(accH[nf][1] + bias[1], 0.f));
      u16 q2 = f2bf(fmaxf(accH[nf][2] + bias[2], 0.f));
      u16 q3 = f2bf(fmaxf(accH[nf][3] + bias[3], 0.f));
      unsigned int lo = (unsigned int)q0 | ((unsigned int)q1 << 16);
      unsigned int hi = (unsigned int)q2 | ((unsigned int)q3 << 16);
      int byte = buf * (BM * HC * 2) + t * 128 + ((hb * 2) ^ ((t & 7) << 4));
      *reinterpret_cast<u32x2*>(reinterpret_cast<char*>(&Hs[0][0]) + byte) = u32x2{lo, hi};
    }
  };

  f32x4 acc[4][4];
#pragma unroll
  for (int a = 0; a < 4; ++a)
#pragma unroll
    for (int b = 0; b < 4; ++b) acc[a][b] = f32x4{0.f, 0.f, 0.f, 0.f};

  auto phase2 = [&](int buf) {
#pragma unroll
    for (int kk = 0; kk < 2; ++kk) {
      bf16x8 b[4];
#pragma unroll
      for (int nf = 0; nf < 4; ++nf) {
        int t = nf * 16 + l15;
        int byte = buf * (BM * HC * 2) + t * 128 + (((kk * 32 + l4 * 8) * 2) ^ ((t & 7) << 4));
        b[nf] = __builtin_bit_cast(bf16x8,
            *reinterpret_cast<const u32x4*>(reinterpret_cast<const char*>(&Hs[0][0]) + byte));
      }
#pragma unroll
      for (int mf = 0; mf < 4; ++mf) {
        bf16x8 a = __builtin_bit_cast(bf16x8, w2buf[mf * 2 + kk]);
#pragma unroll
        for (int nf = 0; nf < 4; ++nf)
          acc[mf][nf] = __builtin_amdgcn_mfma_f32_16x16x32_bf16(a, b[nf], acc[mf][nf], 0, 0, 0);
      }
    }
  };

  phase1(0, 0);
  loadW1(1);
  __syncthreads();

#pragma unroll 1
  for (int c = 0; c < NCHUNK - 1; ++c) {
    phase2(c & 1);          // consumes w2buf(c)
    loadW2(c + 1);          // prefetch next phase2 weights
    phase1(c + 1, (c + 1) & 1);  // consumes w1buf(c+1)
    if (c + 2 < NCHUNK) loadW1(c + 2);
    __syncthreads();
  }
  phase2((NCHUNK - 1) & 1);

  // epilogue: part[slot][tok][o] = w * (acc + b2)  (non-temporal)
#pragma unroll
  for (int mf = 0; mf < 4; ++mf) {
    int ob = wave * 64 + mf * 16 + l4 * 4;
    f32x4 bv = *reinterpret_cast<const f32x4*>(b2 + (size_t)e * OUT_D + ob);
#pragma unroll
    for (int nf = 0; nf < 4; ++nf) {
      int trow = nf * 16 + l15;
      if (base + trow < cnt) {
        int tv = toks[trow];
        int tok = tv & 0xFFFF;
        int slot = tv >> 16;
        float w = gw[trow];
        f32x4 o;
#pragma unroll
        for (int r = 0; r < 4; ++r) o[r] = w * (acc[mf][nf][r] + bv[r]);
        __builtin_nontemporal_store(
            o, reinterpret_cast<f32x4*>(part + ((size_t)slot * T_TOK + tok) * OUT_D + ob));
      }
    }
  }
}

// ---------------- combine: out = part0 + part1 ----------------
__global__ __launch_bounds__(256) void combine_kernel(const float* __restrict__ part,
                                                      float* __restrict__ out) {
  size_t i = (size_t)blockIdx.x * 256 + threadIdx.x;
  f32x4 a = __builtin_nontemporal_load(reinterpret_cast<const f32x4*>(part) + i);
  f32x4 b = __builtin_nontemporal_load(
      reinterpret_cast<const f32x4*>(part + (size_t)T_TOK * OUT_D) + i);
  f32x4 o = a + b;
  __builtin_nontemporal_store(o, reinterpret_cast<f32x4*>(out) + i);
}

// ---------------- launch ----------------
extern "C" void kernel_launch(void* const* d_in, const int* in_sizes, int n_in,
                              void* d_out, int out_size, void* d_ws, size_t ws_size,
                              hipStream_t stream) {
  const float* x  = (const float*)d_in[0];
  const float* Wg = (const float*)d_in[1];
  const float* W1 = (const float*)d_in[2];
  const float* b1 = (const float*)d_in[3];
  const float* W2 = (const float*)d_in[4];
  const float* b2 = (const float*)d_in[5];
  float* out = (float*)d_out;

  char* ws = (char*)d_ws;
  constexpr size_t OFF_XBF  = 0;
  constexpr size_t OFF_W1T  = (size_t)T_TOK * IN_D * 2;
  constexpr size_t OFF_W2T  = OFF_W1T + (size_t)NE * HID_D * IN_D * 2;
  constexpr size_t OFF_CNT  = OFF_W2T + (size_t)NE * OUT_D * HID_D * 2;
  constexpr size_t OFF_LTOK = OFF_CNT + 128;
  constexpr size_t OFF_LW   = OFF_LTOK + (size_t)NE * T_TOK * 4;
  constexpr size_t OFF_PART = OFF_LW + (size_t)NE * T_TOK * 4;

  u16*   xbf      = (u16*)(ws + OFF_XBF);
  u16*   w1t      = (u16*)(ws + OFF_W1T);
  u16*   w2t      = (u16*)(ws + OFF_W2T);
  int*   counts   = (int*)(ws + OFF_CNT);
  int*   list_tok = (int*)(ws + OFF_LTOK);
  float* list_w   = (float*)(ws + OFF_LW);
  float* part     = (float*)(ws + OFF_PART);
  float* probs    = out + (size_t)T_TOK * OUT_D;

  hipMemsetAsync(counts, 0, NE * sizeof(int), stream);

  {
    dim3 g((IN_D / 64) * (HID_D / 64), NE);
    cvt_t_kernel<<<g, 256, 0, stream>>>(W1, w1t, IN_D, HID_D);
  }
  {
    dim3 g((HID_D / 64) * (OUT_D / 64), NE);
    cvt_t_kernel<<<g, 256, 0, stream>>>(W2, w2t, HID_D, OUT_D);
  }
  router_kernel<<<T_TOK / 64, 256, 0, stream>>>(x, Wg, xbf, probs, counts,
                                                list_tok, list_w);

  moe_main_kernel<<<(T_TOK / BM) * NE, 256, 0, stream>>>(
      xbf, w1t, w2t, b1, b2, counts, list_tok, list_w, part);

  combine_kernel<<<(T_TOK * OUT_D / 4) / 256, 256, 0, stream>>>(part, out);
}